// Round 16
// baseline (81.968 us; speedup 1.0000x reference)
//
#include <hip/hip_runtime.h>

// 10 steps of anisotropic 2D heat stencil, 48x48, B=16384.
// ROUND 16: PERSISTENT WAVES - 4 images per wave (grid 4096, TPB=64).
// Per-wave overheads (launch, kernarg, prologue trig/coeffs - which are
// IMAGE-INDEPENDENT, initial load latency, drain) amortize 4x. Parity trick:
// NT=10 even -> image starting in buffer X ends in X, so the other buffer is
// free at switch time; next image's loads issue there immediately after the
// last step, overlapped with the store of the finished image.
// Per image: lane layout 16x4, patch 3x12 as 6 v2f/row, double-buffered
// Jacobi rolled x2, 5-op/cell (cc=1-2ca-2cb precomp), self-tied DPP ghosts
// (boundary lanes = dpp-invalid lanes keep the frozen reflect ghost free),
// 6 bpermutes/step pipelined one step ahead.
// Ghosts = reflect pad of the INITIAL state (reference pads once).

typedef float v2f __attribute__((ext_vector_type(2)));

constexpr int NXY   = 48;
constexpr int CELLS = NXY * NXY;     // 2304
constexpr int NT    = 10;
constexpr int TPB   = 64;            // one wave per block
constexpr int NIMG  = 4;             // images per wave

// lane i <- lane i-1 within each 16-lane DPP row; invalid (i%16==0) keeps oldv
__device__ __forceinline__ float dpp_up(float oldv, float src) {
    return __int_as_float(__builtin_amdgcn_update_dpp(
        __float_as_int(oldv), __float_as_int(src), 0x111, 0xF, 0xF, false));
}
// lane i <- lane i+1; invalid (i%16==15) keeps oldv
__device__ __forceinline__ float dpp_dn(float oldv, float src) {
    return __int_as_float(__builtin_amdgcn_update_dpp(
        __float_as_int(oldv), __float_as_int(src), 0x101, 0xF, 0xF, false));
}

__global__ __launch_bounds__(TPB)
__attribute__((amdgpu_waves_per_eu(2, 4)))
void pde_heat_kernel(
    const float* __restrict__ u0,
    const float* __restrict__ aw,
    const float* __restrict__ bw,
    float* __restrict__ out)
{
    const int lane = threadIdx.x;
    const int r = lane & 15;         // patch-row strip (16 strips of 3 rows)
    const int c = lane >> 4;         // patch-col strip (4 strips of 12 cols)
    const long long img0 = (long long)blockIdx.x * NIMG;
    const float4* __restrict__ u4 = (const float4*)(u0 + img0 * CELLS);
    float4*       __restrict__ o4 = (float4*)(out + img0 * CELLS);

    const int fb = r * 36 + c * 3;   // float4 index of patch (row0, col0)

    // ---- coefficients: IMAGE-INDEPENDENT, computed once per wave ----
    // (v_sin/v_cos take REVOLUTIONS: sin(2pi*x) = v_sin(x))
    // alpha(i) scales axis-0 diff: 0.5*dt/dx^2 = 1.152 ; beta(j): dt/dy^2 = 2.304
    const float a0 = aw[0], a1 = aw[1], a2 = aw[2];
    const float b0 = bw[0], b1 = bw[1], b2 = bw[2];
    float ca[3];
    #pragma unroll
    for (int ii = 0; ii < 3; ++ii) {
        float y = (float)(3 * r + ii) * (1.0f / 47.0f);
        ca[ii] = 1.152f * (a0 + a1 * __builtin_amdgcn_sinf(y)
                              + a2 * __builtin_amdgcn_sinf(2.0f * y));
    }
    v2f cb2[6];
    #pragma unroll
    for (int k = 0; k < 6; ++k) {
        float x0 = (float)(12 * c + 2 * k)     * (1.0f / 47.0f);
        float x1 = (float)(12 * c + 2 * k + 1) * (1.0f / 47.0f);
        cb2[k].x = 2.304f * (b0 + b1 * __builtin_amdgcn_cosf(x0)
                                + b2 * __builtin_amdgcn_cosf(2.0f * x0));
        cb2[k].y = 2.304f * (b0 + b1 * __builtin_amdgcn_cosf(x1)
                                + b2 * __builtin_amdgcn_cosf(2.0f * x1));
    }
    v2f cc[3][6];                    // center coeff cc = 1 - 2ca - 2cb
    #pragma unroll
    for (int ii = 0; ii < 3; ++ii) {
        float t = 1.0f - 2.0f * ca[ii];
        #pragma unroll
        for (int k = 0; k < 6; ++k) {
            cc[ii][k].x = t - 2.0f * cb2[k].x;
            cc[ii][k].y = t - 2.0f * cb2[k].y;
        }
    }

    v2f v[3][6], w[3][6];            // ping-pong state buffers
    v2f ab[6], hb[6];                // persistent tied-DPP halo regs
    float gH[3], hlp[3], hrp[3];     // frozen col ghosts + pipelined shuffles

    const int laneL = lane - 16, laneR = lane + 16;
    const bool cLft = (c == 0), cRgt = (c == 3);

    // ---- helpers (all static buffers; no runtime-indexed arrays) ----
    auto load = [&](v2f (&buf)[3][6], int off4) {
        #pragma unroll
        for (int ii = 0; ii < 3; ++ii)
            #pragma unroll
            for (int k = 0; k < 3; ++k) {
                float4 t = u4[off4 + 12 * ii + k];
                buf[ii][2*k]   = (v2f){t.x, t.y};
                buf[ii][2*k+1] = (v2f){t.z, t.w};
            }
    };
    auto store = [&](const v2f (&buf)[3][6], int off4) {
        #pragma unroll
        for (int ii = 0; ii < 3; ++ii)
            #pragma unroll
            for (int k = 0; k < 3; ++k) {
                float4 t;
                t.x = buf[ii][2*k].x;   t.y = buf[ii][2*k].y;
                t.z = buf[ii][2*k+1].x; t.w = buf[ii][2*k+1].y;
                o4[off4 + 12 * ii + k] = t;
            }
    };
    // (re)initialize all halo state from an image's INITIAL buffer:
    // top ghost (r==0) = row 1 = own buf[1]; bottom (r==15) = row 46 = own
    // buf[1]; boundary lanes are exactly the dpp-invalid lanes -> frozen.
    auto prime = [&](const v2f (&buf)[3][6]) {
        #pragma unroll
        for (int k = 0; k < 6; ++k) { ab[k] = buf[1][k]; hb[k] = buf[1][k]; }
        #pragma unroll
        for (int k = 0; k < 6; ++k) {
            ab[k].x = dpp_up(ab[k].x, buf[2][k].x);
            ab[k].y = dpp_up(ab[k].y, buf[2][k].y);
            hb[k].x = dpp_dn(hb[k].x, buf[0][k].x);
            hb[k].y = dpp_dn(hb[k].y, buf[0][k].y);
        }
        #pragma unroll
        for (int ii = 0; ii < 3; ++ii)
            gH[ii] = cLft ? buf[ii][0].y : buf[ii][5].x;
        #pragma unroll
        for (int ii = 0; ii < 3; ++ii) {
            hlp[ii] = __shfl(buf[ii][5].y, laneL);   // left nb's col 11
            hrp[ii] = __shfl(buf[ii][0].x, laneR);   // right nb's col 0
        }
    };
    // one Jacobi step using pre-staged halos; stages next step's halos from dst
    auto step = [&](const v2f (&src)[3][6], v2f (&dst)[3][6]) {
        float hl[3], hr[3];
        #pragma unroll
        for (int ii = 0; ii < 3; ++ii) {
            hl[ii] = cLft ? gH[ii] : hlp[ii];
            hr[ii] = cRgt ? gH[ii] : hrp[ii];
        }
        // row 0 (row above = ab)
        #pragma unroll
        for (int k = 0; k < 6; ++k) {
            v2f cv = src[0][k];
            v2f s1 = ab[k] + src[1][k];
            v2f s2;
            s2.x = ((k > 0) ? src[0][k-1].y : hl[0]) + cv.y;
            s2.y = cv.x + ((k < 5) ? src[0][k+1].x : hr[0]);
            dst[0][k] = cc[0][k] * cv + ca[0] * s1 + cb2[k] * s2;
        }
        // row 1 (fully local)
        #pragma unroll
        for (int k = 0; k < 6; ++k) {
            v2f cv = src[1][k];
            v2f s1 = src[0][k] + src[2][k];
            v2f s2;
            s2.x = ((k > 0) ? src[1][k-1].y : hl[1]) + cv.y;
            s2.y = cv.x + ((k < 5) ? src[1][k+1].x : hr[1]);
            dst[1][k] = cc[1][k] * cv + ca[1] * s1 + cb2[k] * s2;
        }
        // row 2 (row below = hb)
        #pragma unroll
        for (int k = 0; k < 6; ++k) {
            v2f cv = src[2][k];
            v2f s1 = src[1][k] + hb[k];
            v2f s2;
            s2.x = ((k > 0) ? src[2][k-1].y : hl[2]) + cv.y;
            s2.y = cv.x + ((k < 5) ? src[2][k+1].x : hr[2]);
            dst[2][k] = cc[2][k] * cv + ca[2] * s1 + cb2[k] * s2;
        }
        // stage next step's halos from dst (tied dpp + pipelined shuffles);
        // at image end this is harmless - prime() overwrites everything
        #pragma unroll
        for (int k = 0; k < 6; ++k) {
            ab[k].x = dpp_up(ab[k].x, dst[2][k].x);
            ab[k].y = dpp_up(ab[k].y, dst[2][k].y);
            hb[k].x = dpp_dn(hb[k].x, dst[0][k].x);
            hb[k].y = dpp_dn(hb[k].y, dst[0][k].y);
        }
        #pragma unroll
        for (int ii = 0; ii < 3; ++ii) {
            hlp[ii] = __shfl(dst[ii][5].y, laneL);
            hrp[ii] = __shfl(dst[ii][0].x, laneR);
        }
    };

    // ---- image pipeline: load0 -> (steps, load next into freed buffer,
    //      store, prime) x NIMG. NT even => image starting in X ends in X ----
    load(v, fb);
    prime(v);
    #pragma unroll 1
    for (int p = 0; p < NIMG / 2; ++p) {
        const int i0 = 2 * p;
        #pragma unroll 1
        for (int it = 0; it < NT / 2; ++it) { step(v, w); step(w, v); }
        load(w, (i0 + 1) * (CELLS / 4) + fb);      // next image into freed w
        store(v, i0 * (CELLS / 4) + fb);           // overlaps load latency
        prime(w);
        #pragma unroll 1
        for (int it = 0; it < NT / 2; ++it) { step(w, v); step(v, w); }
        if (p + 1 < NIMG / 2) load(v, (i0 + 2) * (CELLS / 4) + fb);
        store(w, (i0 + 1) * (CELLS / 4) + fb);
        if (p + 1 < NIMG / 2) prime(v);
    }
}

extern "C" void kernel_launch(void* const* d_in, const int* in_sizes, int n_in,
                              void* d_out, int out_size, void* d_ws, size_t ws_size,
                              hipStream_t stream) {
    const float* u0 = (const float*)d_in[0];
    const float* aw = (const float*)d_in[1];
    const float* bw = (const float*)d_in[2];
    float* out = (float*)d_out;

    const int B = in_sizes[0] / CELLS;   // 16384
    pde_heat_kernel<<<B / NIMG, TPB, 0, stream>>>(u0, aw, bw, out);
}

// Round 18
// 76.210 us; speedup vs baseline: 1.0756x; 1.0756x over previous
//
#include <hip/hip_runtime.h>

// 10 steps of anisotropic 2D heat stencil, 48x48, B=16384.
// Wave = image = block (TPB=64), grid 16384.
// Lane layout 16x4: (r,c)=(lane&15, lane>>4), patch 3x12 as 6 v2f/row.
// Double-buffered Jacobi, 5-op/cell (cc=1-2ca-2cb precomp), self-tied DPP
// ghosts (boundary lanes = dpp-invalid lanes keep frozen reflect ghost free).
// Full 10-step unroll; interior column-pairs before boundary pairs; per-row
// next-step shuffle issue.
// ROUND 18 FIX: round 17 clobbered hb (row-below halo) at ii==0 before its
// consumer (row 2, same step) read it - WAR hazard from over-eager staging.
// hb is now restaged at ii==2, AFTER its last consumer; dst[0] is final by
// then so the data is identical. ab stays: consumed ii==0, staged ii==2.
// Ghosts = reflect pad of the INITIAL state (reference pads once).

typedef float v2f __attribute__((ext_vector_type(2)));

constexpr int NXY   = 48;
constexpr int CELLS = NXY * NXY;     // 2304
constexpr int NT    = 10;
constexpr int TPB   = 64;            // one wave per block

// lane i <- lane i-1 within each 16-lane DPP row; invalid (i%16==0) keeps oldv
__device__ __forceinline__ float dpp_up(float oldv, float src) {
    return __int_as_float(__builtin_amdgcn_update_dpp(
        __float_as_int(oldv), __float_as_int(src), 0x111, 0xF, 0xF, false));
}
// lane i <- lane i+1; invalid (i%16==15) keeps oldv
__device__ __forceinline__ float dpp_dn(float oldv, float src) {
    return __int_as_float(__builtin_amdgcn_update_dpp(
        __float_as_int(oldv), __float_as_int(src), 0x101, 0xF, 0xF, false));
}

__global__ __launch_bounds__(TPB)
__attribute__((amdgpu_waves_per_eu(2, 4)))
void pde_heat_kernel(
    const float* __restrict__ u0,
    const float* __restrict__ aw,
    const float* __restrict__ bw,
    float* __restrict__ out)
{
    const int lane = threadIdx.x;
    const int img  = blockIdx.x;
    const int r = lane & 15;         // patch-row strip (16 strips of 3 rows)
    const int c = lane >> 4;         // patch-col strip (4 strips of 12 cols)
    const float4* __restrict__ u4 = (const float4*)(u0 + (long long)img * CELLS);
    float4*       __restrict__ o4 = (float4*)(out + (long long)img * CELLS);

    const int fb = r * 36 + c * 3;   // float4 index of patch (row0, col0)

    // ---- direct load: 9 x global_load_dwordx4 -> 6 x v2f per row ----
    v2f v[3][6], w[3][6];
    #pragma unroll
    for (int ii = 0; ii < 3; ++ii)
        #pragma unroll
        for (int k = 0; k < 3; ++k) {
            float4 t = u4[fb + 12 * ii + k];
            v[ii][2*k]   = (v2f){t.x, t.y};
            v[ii][2*k+1] = (v2f){t.z, t.w};
        }

    // ---- coefficients (v_sin/v_cos take REVOLUTIONS: sin(2pi*x) = v_sin(x)) ----
    // alpha(i) scales axis-0 diff: 0.5*dt/dx^2 = 1.152 ; beta(j): dt/dy^2 = 2.304
    const float a0 = aw[0], a1 = aw[1], a2 = aw[2];
    const float b0 = bw[0], b1 = bw[1], b2 = bw[2];
    float ca[3];
    #pragma unroll
    for (int ii = 0; ii < 3; ++ii) {
        float y = (float)(3 * r + ii) * (1.0f / 47.0f);
        ca[ii] = 1.152f * (a0 + a1 * __builtin_amdgcn_sinf(y)
                              + a2 * __builtin_amdgcn_sinf(2.0f * y));
    }
    v2f cb2[6];
    #pragma unroll
    for (int k = 0; k < 6; ++k) {
        float x0 = (float)(12 * c + 2 * k)     * (1.0f / 47.0f);
        float x1 = (float)(12 * c + 2 * k + 1) * (1.0f / 47.0f);
        cb2[k].x = 2.304f * (b0 + b1 * __builtin_amdgcn_cosf(x0)
                                + b2 * __builtin_amdgcn_cosf(2.0f * x0));
        cb2[k].y = 2.304f * (b0 + b1 * __builtin_amdgcn_cosf(x1)
                                + b2 * __builtin_amdgcn_cosf(2.0f * x1));
    }
    v2f cc[3][6];                    // center coeff cc = 1 - 2ca - 2cb
    #pragma unroll
    for (int ii = 0; ii < 3; ++ii) {
        float t = 1.0f - 2.0f * ca[ii];
        #pragma unroll
        for (int k = 0; k < 6; ++k) {
            cc[ii][k].x = t - 2.0f * cb2[k].x;
            cc[ii][k].y = t - 2.0f * cb2[k].y;
        }
    }

    // ---- persistent halo regs, init'd to the frozen ghost ----
    // top ghost (r==0) = u0 row 1 = own v[1]; bottom (r==15) = row 46 = own
    // v[1]. Boundary lanes are exactly the dpp-invalid lanes -> stay frozen.
    v2f ab[6], hb[6];
    #pragma unroll
    for (int k = 0; k < 6; ++k) { ab[k] = v[1][k]; hb[k] = v[1][k]; }

    float gH[3];   // frozen horizontal ghosts: col 1 / col 46 (own initial)
    #pragma unroll
    for (int ii = 0; ii < 3; ++ii) gH[ii] = (c == 0) ? v[ii][0].y : v[ii][5].x;

    const int laneL = lane - 16, laneR = lane + 16;
    const bool cLft = (c == 0), cRgt = (c == 3);

    // prime both halo pipelines for step 0 (from initial state)
    #pragma unroll
    for (int k = 0; k < 6; ++k) {
        ab[k].x = dpp_up(ab[k].x, v[2][k].x);
        ab[k].y = dpp_up(ab[k].y, v[2][k].y);
        hb[k].x = dpp_dn(hb[k].x, v[0][k].x);
        hb[k].y = dpp_dn(hb[k].y, v[0][k].y);
    }
    float hlp[3], hrp[3];
    #pragma unroll
    for (int ii = 0; ii < 3; ++ii) {
        hlp[ii] = __shfl(v[ii][5].y, laneL);   // left neighbor's col 11
        hrp[ii] = __shfl(v[ii][0].x, laneR);   // right neighbor's col 0
    }

    // one cell-pair update (5 packed ops + 2 scalar adds)
    auto cellpair = [&](int ii, int k, const v2f (&rowU)[6], const v2f (&rowM)[6],
                        const v2f (&rowD)[6], float lf, float rt) -> v2f {
        v2f cv = rowM[k];
        v2f s1 = rowU[k] + rowD[k];
        v2f s2;
        s2.x = lf + cv.y;
        s2.y = cv.x + rt;
        return cc[ii][k] * cv + ca[ii] * s1 + cb2[k] * s2;
    };

    // one Jacobi step: interior pairs first (halo-free -> covers halo waits);
    // shuffles issued per-row right after the row finalizes; ab restaged at
    // ii==2 (consumed ii==0); hb restaged at ii==2 AFTER its consumer (row 2)
    auto step = [&](const v2f (&src)[3][6], v2f (&dst)[3][6], bool stage) {
        float hl[3], hr[3];
        #pragma unroll
        for (int ii = 0; ii < 3; ++ii) {
            hl[ii] = cLft ? gH[ii] : hlp[ii];
            hr[ii] = cRgt ? gH[ii] : hrp[ii];
        }
        #pragma unroll
        for (int ii = 0; ii < 3; ++ii) {
            const v2f (&rowU)[6] = (ii == 0) ? ab : src[ii - 1];
            const v2f (&rowD)[6] = (ii == 2) ? hb : src[ii + 1];
            // interior pairs k=1..4: no halos needed
            #pragma unroll
            for (int k = 1; k < 5; ++k)
                dst[ii][k] = cellpair(ii, k, rowU, src[ii], rowD,
                                      src[ii][k-1].y, src[ii][k+1].x);
            // boundary pairs
            dst[ii][0] = cellpair(ii, 0, rowU, src[ii], rowD,
                                  hl[ii], src[ii][1].x);
            dst[ii][5] = cellpair(ii, 5, rowU, src[ii], rowD,
                                  src[ii][4].y, hr[ii]);
            if (stage) {
                // this row's next-step horizontal halos (hl/hr already latched)
                hlp[ii] = __shfl(dst[ii][5].y, laneL);
                hrp[ii] = __shfl(dst[ii][0].x, laneR);
                if (ii == 2) {
                    // vertical halos for next step - AFTER all consumers:
                    // ab (consumed ii==0) from dst row 2; hb (consumed ii==2,
                    // just now) from dst row 0 (final since ii==0)
                    #pragma unroll
                    for (int k = 0; k < 6; ++k) {
                        ab[k].x = dpp_up(ab[k].x, dst[2][k].x);
                        ab[k].y = dpp_up(ab[k].y, dst[2][k].y);
                        hb[k].x = dpp_dn(hb[k].x, dst[0][k].x);
                        hb[k].y = dpp_dn(hb[k].y, dst[0][k].y);
                    }
                }
            }
        }
    };

    // ---- time loop: FULLY UNROLLED (buffer choice folds statically) ----
    #pragma unroll
    for (int t = 0; t < NT; ++t) {
        if ((t & 1) == 0) step(v, w, t != NT - 1);
        else              step(w, v, t != NT - 1);
    }
    // NT even -> final state in v

    // ---- direct store: 9 x global_store_dwordx4 ----
    #pragma unroll
    for (int ii = 0; ii < 3; ++ii)
        #pragma unroll
        for (int k = 0; k < 3; ++k) {
            float4 t;
            t.x = v[ii][2*k].x;   t.y = v[ii][2*k].y;
            t.z = v[ii][2*k+1].x; t.w = v[ii][2*k+1].y;
            o4[fb + 12 * ii + k] = t;
        }
}

extern "C" void kernel_launch(void* const* d_in, const int* in_sizes, int n_in,
                              void* d_out, int out_size, void* d_ws, size_t ws_size,
                              hipStream_t stream) {
    const float* u0 = (const float*)d_in[0];
    const float* aw = (const float*)d_in[1];
    const float* bw = (const float*)d_in[2];
    float* out = (float*)d_out;

    const int B = in_sizes[0] / CELLS;   // 16384
    pde_heat_kernel<<<B, TPB, 0, stream>>>(u0, aw, bw, out);
}

// Round 19
// 75.806 us; speedup vs baseline: 1.0813x; 1.0053x over previous
//
#include <hip/hip_runtime.h>

// 10 steps of anisotropic 2D heat stencil, 48x48, B=16384.
// Wave = image = block (TPB=64), grid 16384.
// Lane layout 16x4: (r,c)=(lane&15, lane>>4), patch 3x12 as 6 v2f/row.
// Double-buffered Jacobi, 5-op/cell (cc=1-2ca-2cb precomp), self-tied DPP
// ghosts (boundary lanes = dpp-invalid lanes keep frozen reflect ghost free).
// Full 10-step unroll; interior column-pairs before boundary pairs; per-row
// next-step shuffle issue.
// ROUND 18 FIX: round 17 clobbered hb (row-below halo) at ii==0 before its
// consumer (row 2, same step) read it - WAR hazard from over-eager staging.
// hb is now restaged at ii==2, AFTER its last consumer; dst[0] is final by
// then so the data is identical. ab stays: consumed ii==0, staged ii==2.
// Ghosts = reflect pad of the INITIAL state (reference pads once).

typedef float v2f __attribute__((ext_vector_type(2)));

constexpr int NXY   = 48;
constexpr int CELLS = NXY * NXY;     // 2304
constexpr int NT    = 10;
constexpr int TPB   = 64;            // one wave per block

// lane i <- lane i-1 within each 16-lane DPP row; invalid (i%16==0) keeps oldv
__device__ __forceinline__ float dpp_up(float oldv, float src) {
    return __int_as_float(__builtin_amdgcn_update_dpp(
        __float_as_int(oldv), __float_as_int(src), 0x111, 0xF, 0xF, false));
}
// lane i <- lane i+1; invalid (i%16==15) keeps oldv
__device__ __forceinline__ float dpp_dn(float oldv, float src) {
    return __int_as_float(__builtin_amdgcn_update_dpp(
        __float_as_int(oldv), __float_as_int(src), 0x101, 0xF, 0xF, false));
}

__global__ __launch_bounds__(TPB)
__attribute__((amdgpu_waves_per_eu(2, 4)))
void pde_heat_kernel(
    const float* __restrict__ u0,
    const float* __restrict__ aw,
    const float* __restrict__ bw,
    float* __restrict__ out)
{
    const int lane = threadIdx.x;
    const int img  = blockIdx.x;
    const int r = lane & 15;         // patch-row strip (16 strips of 3 rows)
    const int c = lane >> 4;         // patch-col strip (4 strips of 12 cols)
    const float4* __restrict__ u4 = (const float4*)(u0 + (long long)img * CELLS);
    float4*       __restrict__ o4 = (float4*)(out + (long long)img * CELLS);

    const int fb = r * 36 + c * 3;   // float4 index of patch (row0, col0)

    // ---- direct load: 9 x global_load_dwordx4 -> 6 x v2f per row ----
    v2f v[3][6], w[3][6];
    #pragma unroll
    for (int ii = 0; ii < 3; ++ii)
        #pragma unroll
        for (int k = 0; k < 3; ++k) {
            float4 t = u4[fb + 12 * ii + k];
            v[ii][2*k]   = (v2f){t.x, t.y};
            v[ii][2*k+1] = (v2f){t.z, t.w};
        }

    // ---- coefficients (v_sin/v_cos take REVOLUTIONS: sin(2pi*x) = v_sin(x)) ----
    // alpha(i) scales axis-0 diff: 0.5*dt/dx^2 = 1.152 ; beta(j): dt/dy^2 = 2.304
    const float a0 = aw[0], a1 = aw[1], a2 = aw[2];
    const float b0 = bw[0], b1 = bw[1], b2 = bw[2];
    float ca[3];
    #pragma unroll
    for (int ii = 0; ii < 3; ++ii) {
        float y = (float)(3 * r + ii) * (1.0f / 47.0f);
        ca[ii] = 1.152f * (a0 + a1 * __builtin_amdgcn_sinf(y)
                              + a2 * __builtin_amdgcn_sinf(2.0f * y));
    }
    v2f cb2[6];
    #pragma unroll
    for (int k = 0; k < 6; ++k) {
        float x0 = (float)(12 * c + 2 * k)     * (1.0f / 47.0f);
        float x1 = (float)(12 * c + 2 * k + 1) * (1.0f / 47.0f);
        cb2[k].x = 2.304f * (b0 + b1 * __builtin_amdgcn_cosf(x0)
                                + b2 * __builtin_amdgcn_cosf(2.0f * x0));
        cb2[k].y = 2.304f * (b0 + b1 * __builtin_amdgcn_cosf(x1)
                                + b2 * __builtin_amdgcn_cosf(2.0f * x1));
    }
    v2f cc[3][6];                    // center coeff cc = 1 - 2ca - 2cb
    #pragma unroll
    for (int ii = 0; ii < 3; ++ii) {
        float t = 1.0f - 2.0f * ca[ii];
        #pragma unroll
        for (int k = 0; k < 6; ++k) {
            cc[ii][k].x = t - 2.0f * cb2[k].x;
            cc[ii][k].y = t - 2.0f * cb2[k].y;
        }
    }

    // ---- persistent halo regs, init'd to the frozen ghost ----
    // top ghost (r==0) = u0 row 1 = own v[1]; bottom (r==15) = row 46 = own
    // v[1]. Boundary lanes are exactly the dpp-invalid lanes -> stay frozen.
    v2f ab[6], hb[6];
    #pragma unroll
    for (int k = 0; k < 6; ++k) { ab[k] = v[1][k]; hb[k] = v[1][k]; }

    float gH[3];   // frozen horizontal ghosts: col 1 / col 46 (own initial)
    #pragma unroll
    for (int ii = 0; ii < 3; ++ii) gH[ii] = (c == 0) ? v[ii][0].y : v[ii][5].x;

    const int laneL = lane - 16, laneR = lane + 16;
    const bool cLft = (c == 0), cRgt = (c == 3);

    // prime both halo pipelines for step 0 (from initial state)
    #pragma unroll
    for (int k = 0; k < 6; ++k) {
        ab[k].x = dpp_up(ab[k].x, v[2][k].x);
        ab[k].y = dpp_up(ab[k].y, v[2][k].y);
        hb[k].x = dpp_dn(hb[k].x, v[0][k].x);
        hb[k].y = dpp_dn(hb[k].y, v[0][k].y);
    }
    float hlp[3], hrp[3];
    #pragma unroll
    for (int ii = 0; ii < 3; ++ii) {
        hlp[ii] = __shfl(v[ii][5].y, laneL);   // left neighbor's col 11
        hrp[ii] = __shfl(v[ii][0].x, laneR);   // right neighbor's col 0
    }

    // one cell-pair update (5 packed ops + 2 scalar adds)
    auto cellpair = [&](int ii, int k, const v2f (&rowU)[6], const v2f (&rowM)[6],
                        const v2f (&rowD)[6], float lf, float rt) -> v2f {
        v2f cv = rowM[k];
        v2f s1 = rowU[k] + rowD[k];
        v2f s2;
        s2.x = lf + cv.y;
        s2.y = cv.x + rt;
        return cc[ii][k] * cv + ca[ii] * s1 + cb2[k] * s2;
    };

    // one Jacobi step: interior pairs first (halo-free -> covers halo waits);
    // shuffles issued per-row right after the row finalizes; ab restaged at
    // ii==2 (consumed ii==0); hb restaged at ii==2 AFTER its consumer (row 2)
    auto step = [&](const v2f (&src)[3][6], v2f (&dst)[3][6], bool stage) {
        float hl[3], hr[3];
        #pragma unroll
        for (int ii = 0; ii < 3; ++ii) {
            hl[ii] = cLft ? gH[ii] : hlp[ii];
            hr[ii] = cRgt ? gH[ii] : hrp[ii];
        }
        #pragma unroll
        for (int ii = 0; ii < 3; ++ii) {
            const v2f (&rowU)[6] = (ii == 0) ? ab : src[ii - 1];
            const v2f (&rowD)[6] = (ii == 2) ? hb : src[ii + 1];
            // interior pairs k=1..4: no halos needed
            #pragma unroll
            for (int k = 1; k < 5; ++k)
                dst[ii][k] = cellpair(ii, k, rowU, src[ii], rowD,
                                      src[ii][k-1].y, src[ii][k+1].x);
            // boundary pairs
            dst[ii][0] = cellpair(ii, 0, rowU, src[ii], rowD,
                                  hl[ii], src[ii][1].x);
            dst[ii][5] = cellpair(ii, 5, rowU, src[ii], rowD,
                                  src[ii][4].y, hr[ii]);
            if (stage) {
                // this row's next-step horizontal halos (hl/hr already latched)
                hlp[ii] = __shfl(dst[ii][5].y, laneL);
                hrp[ii] = __shfl(dst[ii][0].x, laneR);
                if (ii == 2) {
                    // vertical halos for next step - AFTER all consumers:
                    // ab (consumed ii==0) from dst row 2; hb (consumed ii==2,
                    // just now) from dst row 0 (final since ii==0)
                    #pragma unroll
                    for (int k = 0; k < 6; ++k) {
                        ab[k].x = dpp_up(ab[k].x, dst[2][k].x);
                        ab[k].y = dpp_up(ab[k].y, dst[2][k].y);
                        hb[k].x = dpp_dn(hb[k].x, dst[0][k].x);
                        hb[k].y = dpp_dn(hb[k].y, dst[0][k].y);
                    }
                }
            }
        }
    };

    // ---- time loop: FULLY UNROLLED (buffer choice folds statically) ----
    #pragma unroll
    for (int t = 0; t < NT; ++t) {
        if ((t & 1) == 0) step(v, w, t != NT - 1);
        else              step(w, v, t != NT - 1);
    }
    // NT even -> final state in v

    // ---- direct store: 9 x global_store_dwordx4 ----
    #pragma unroll
    for (int ii = 0; ii < 3; ++ii)
        #pragma unroll
        for (int k = 0; k < 3; ++k) {
            float4 t;
            t.x = v[ii][2*k].x;   t.y = v[ii][2*k].y;
            t.z = v[ii][2*k+1].x; t.w = v[ii][2*k+1].y;
            o4[fb + 12 * ii + k] = t;
        }
}

extern "C" void kernel_launch(void* const* d_in, const int* in_sizes, int n_in,
                              void* d_out, int out_size, void* d_ws, size_t ws_size,
                              hipStream_t stream) {
    const float* u0 = (const float*)d_in[0];
    const float* aw = (const float*)d_in[1];
    const float* bw = (const float*)d_in[2];
    float* out = (float*)d_out;

    const int B = in_sizes[0] / CELLS;   // 16384
    pde_heat_kernel<<<B, TPB, 0, stream>>>(u0, aw, bw, out);
}